// Round 1
// baseline (7644.923 us; speedup 1.0000x reference)
//
#include <hip/hip_runtime.h>
#include <hip/hip_bf16.h>
#include <stdint.h>

#define KG 32
#define GG 2048
#define DD 2048
#define BB 2048
#define NN (KG*GG)   // 65536

#define BM 128
#define BN 128
#define BK 32

// ---- workspace layout (bytes) ----
// [0       , 524288 )  u64 packed[65536]        (zeroed)
// [524288  , 786432 )  f32 maxv[65536]
// [786432  , 1048576)  i32 idx[65536]
// [1048576 , 1310720)  i32 counts[65536]        (zeroed)
// [1310720 , 1310728)  f32 accum[2] = {e, tv}   (zeroed)
// [1310784 , 1441856)  f32 varS1[16*2048]
// [1441856 , 1572928)  f32 varS2[16*2048]

__device__ __forceinline__ unsigned int f2ord(float f) {
    unsigned int u = __float_as_uint(f);
    return (u & 0x80000000u) ? ~u : (u | 0x80000000u);
}
__device__ __forceinline__ float ord2f(unsigned int u) {
    u = (u & 0x80000000u) ? (u & 0x7FFFFFFFu) : ~u;
    return __uint_as_float(u);
}

// ---------------- variance pass 1: per (b-chunk, d) partial sums ----------------
__global__ __launch_bounds__(256) void var1_kernel(const float* __restrict__ x,
                                                   const float* __restrict__ b_dec,
                                                   float* __restrict__ varS1,
                                                   float* __restrict__ varS2) {
    int bx = blockIdx.x;            // 128 blocks
    int dchunk = bx & 7;            // 8 chunks of 256 d's
    int bchunk = bx >> 3;           // 16 chunks of 128 b's
    int d = dchunk * 256 + threadIdx.x;
    float bd = b_dec[d];
    float s1 = 0.f, s2 = 0.f;
    for (int bb = 0; bb < 128; ++bb) {
        float v = x[(size_t)(bchunk * 128 + bb) * DD + d] - bd;
        s1 += v;
        s2 += v * v;
    }
    varS1[bchunk * DD + d] = s1;
    varS2[bchunk * DD + d] = s2;
}

// ---------------- variance pass 2: total_variance -> accum[1] ----------------
__global__ __launch_bounds__(256) void var2_kernel(const float* __restrict__ varS1,
                                                   const float* __restrict__ varS2,
                                                   float* __restrict__ accum) {
    int d = blockIdx.x * 256 + threadIdx.x;   // 8 blocks
    float s1 = 0.f, s2 = 0.f;
    for (int c = 0; c < 16; ++c) {
        s1 += varS1[c * DD + d];
        s2 += varS2[c * DD + d];
    }
    float tvd = s2 - s1 * s1 * (1.0f / BB);
    #pragma unroll
    for (int off = 32; off; off >>= 1) tvd += __shfl_down(tvd, off, 64);
    if ((threadIdx.x & 63) == 0) atomicAdd(&accum[1], tvd);
}

// ---------------- fused GEMM (acts = (x-b_dec) @ enc^T + b_enc) + argmax ----------------
__global__ __launch_bounds__(256) void gemm_argmax_kernel(
        const float* __restrict__ x, const float* __restrict__ enc,
        const float* __restrict__ b_enc, const float* __restrict__ b_dec,
        unsigned long long* __restrict__ packed) {
    __shared__ float As[BK][BM];
    __shared__ float Bs[BK][BN];

    // XCD-chunked remap: each XCD owns a contiguous range of n-tiles so the
    // 16 m-tiles sharing one encoder panel are co-resident in one L2.
    int wg = blockIdx.x;                       // 8192 blocks
    int lg = (wg & 7) * 1024 + (wg >> 3);      // bijective: 8192 % 8 == 0
    int n_tile = lg >> 4;                      // 512 n-tiles
    int m_tile = lg & 15;                      // 16 m-tiles
    int row0 = m_tile * BM;
    int col0 = n_tile * BN;

    int tid = threadIdx.x;
    int tx = tid & 15, ty = tid >> 4;          // 16x16 thread grid, 8x8 micro-tile
    int lr = tid >> 3;                         // staging row 0..31
    int lc = (tid & 7) << 2;                   // staging col 0,4,...,28

    float acc[8][8];
    #pragma unroll
    for (int i = 0; i < 8; ++i)
        #pragma unroll
        for (int j = 0; j < 8; ++j) acc[i][j] = 0.f;

    for (int k0 = 0; k0 < DD; k0 += BK) {
        #pragma unroll
        for (int p = 0; p < 4; ++p) {
            int r = lr + p * 32;
            float4 a  = *(const float4*)(x + (size_t)(row0 + r) * DD + k0 + lc);
            float4 bd = *(const float4*)(b_dec + k0 + lc);
            As[lc + 0][r] = a.x - bd.x;
            As[lc + 1][r] = a.y - bd.y;
            As[lc + 2][r] = a.z - bd.z;
            As[lc + 3][r] = a.w - bd.w;
            float4 e = *(const float4*)(enc + (size_t)(col0 + r) * DD + k0 + lc);
            Bs[lc + 0][r] = e.x;
            Bs[lc + 1][r] = e.y;
            Bs[lc + 2][r] = e.z;
            Bs[lc + 3][r] = e.w;
        }
        __syncthreads();
        #pragma unroll
        for (int kk = 0; kk < BK; ++kk) {
            float ar[8], br[8];
            *(float4*)&ar[0] = *(const float4*)&As[kk][ty * 8];
            *(float4*)&ar[4] = *(const float4*)&As[kk][ty * 8 + 4];
            *(float4*)&br[0] = *(const float4*)&Bs[kk][tx * 8];
            *(float4*)&br[4] = *(const float4*)&Bs[kk][tx * 8 + 4];
            #pragma unroll
            for (int i = 0; i < 8; ++i)
                #pragma unroll
                for (int j = 0; j < 8; ++j)
                    acc[i][j] = fmaf(ar[i], br[j], acc[i][j]);
        }
        __syncthreads();
    }

    // epilogue: + b_enc, per-row argmax over this 128-col tile, merge via atomicMax
    int kg = col0 >> 11;                 // tile lies entirely in one k-group
    int gbase = (col0 & (GG - 1)) + tx * 8;
    float be[8];
    *(float4*)&be[0] = *(const float4*)(b_enc + kg * GG + gbase);
    *(float4*)&be[4] = *(const float4*)(b_enc + kg * GG + gbase + 4);

    #pragma unroll
    for (int i = 0; i < 8; ++i) {
        float v = acc[i][0] + be[0];
        int gi = gbase;
        #pragma unroll
        for (int j = 1; j < 8; ++j) {
            float w = acc[i][j] + be[j];
            if (w > v) { v = w; gi = gbase + j; }   // strict > keeps first index on tie
        }
        unsigned long long pk =
            ((unsigned long long)f2ord(v) << 32) | (unsigned int)(GG - 1 - gi);
        // reduce across the 16 tx-lanes (lane bits 0..3)
        #pragma unroll
        for (int s = 1; s < 16; s <<= 1) {
            unsigned long long o = __shfl_xor(pk, s, 64);
            pk = (o > pk) ? o : pk;
        }
        if (tx == 0) {
            int row = row0 + ty * 8 + i;
            atomicMax(&packed[(size_t)row * KG + kg], pk);
        }
    }
}

// ---------------- decode packed -> maxv/idx, histogram counts ----------------
__global__ __launch_bounds__(256) void extract_kernel(
        const unsigned long long* __restrict__ packed,
        float* __restrict__ maxv, int* __restrict__ idx, int* __restrict__ counts) {
    int i = blockIdx.x * 256 + threadIdx.x;    // i = b*KG + k, 65536 total
    unsigned long long pk = packed[i];
    float v = ord2f((unsigned int)(pk >> 32));
    int g = GG - 1 - (int)(pk & 0xFFFFFFFFu);
    maxv[i] = v;
    idx[i] = g;
    int k = i & (KG - 1);
    atomicAdd(&counts[k * GG + g], 1);
}

// ---------------- reconstruction + squared error -> accum[0] ----------------
__global__ __launch_bounds__(256) void recon_kernel(
        const float* __restrict__ x, const float* __restrict__ decoder,
        const float* __restrict__ b_dec, const float* __restrict__ maxv,
        const int* __restrict__ idx, float* __restrict__ accum) {
    int b = blockIdx.x;                        // 2048 blocks
    int t = threadIdx.x;
    __shared__ float sv[KG];
    __shared__ int si[KG];
    if (t < KG) { sv[t] = maxv[b * KG + t]; si[t] = idx[b * KG + t]; }
    __syncthreads();

    int d0 = t * 4;
    int d1 = 1024 + t * 4;
    float4 x0  = *(const float4*)(x + (size_t)b * DD + d0);
    float4 x1  = *(const float4*)(x + (size_t)b * DD + d1);
    float4 bd0 = *(const float4*)(b_dec + d0);
    float4 bd1 = *(const float4*)(b_dec + d1);
    float4 o0 = {0.f, 0.f, 0.f, 0.f}, o1 = {0.f, 0.f, 0.f, 0.f};

    #pragma unroll 4
    for (int k = 0; k < KG; ++k) {
        float w = sv[k];
        const float* dr = decoder + ((size_t)k * GG + si[k]) * DD;
        float4 r0 = *(const float4*)(dr + d0);
        float4 r1 = *(const float4*)(dr + d1);
        o0.x += w * r0.x; o0.y += w * r0.y; o0.z += w * r0.z; o0.w += w * r0.w;
        o1.x += w * r1.x; o1.y += w * r1.y; o1.z += w * r1.z; o1.w += w * r1.w;
    }
    // diff = xc - out = (x - b_dec) - (o + b_dec)
    float dx, s = 0.f;
    dx = (x0.x - bd0.x) - (o0.x + bd0.x); s += dx * dx;
    dx = (x0.y - bd0.y) - (o0.y + bd0.y); s += dx * dx;
    dx = (x0.z - bd0.z) - (o0.z + bd0.z); s += dx * dx;
    dx = (x0.w - bd0.w) - (o0.w + bd0.w); s += dx * dx;
    dx = (x1.x - bd1.x) - (o1.x + bd1.x); s += dx * dx;
    dx = (x1.y - bd1.y) - (o1.y + bd1.y); s += dx * dx;
    dx = (x1.z - bd1.z) - (o1.z + bd1.z); s += dx * dx;
    dx = (x1.w - bd1.w) - (o1.w + bd1.w); s += dx * dx;

    #pragma unroll
    for (int off = 32; off; off >>= 1) s += __shfl_down(s, off, 64);
    if ((t & 63) == 0) atomicAdd(&accum[0], s);
}

// ---------------- finalize: fvu, counts->float, aux ----------------
__global__ __launch_bounds__(256) void finalize_kernel(
        const float* __restrict__ accum, const int* __restrict__ counts,
        float* __restrict__ out) {
    int i = blockIdx.x * 256 + threadIdx.x;
    if (i < NN) out[1 + i] = (float)counts[i];
    if (i == 0) {
        out[0] = accum[0] / accum[1];
        out[1 + NN] = 0.0f;
    }
}

extern "C" void kernel_launch(void* const* d_in, const int* in_sizes, int n_in,
                              void* d_out, int out_size, void* d_ws, size_t ws_size,
                              hipStream_t stream) {
    const float* x       = (const float*)d_in[0];
    const float* encoder = (const float*)d_in[1];
    const float* b_enc   = (const float*)d_in[2];
    const float* decoder = (const float*)d_in[3];
    const float* b_dec   = (const float*)d_in[4];
    float* out = (float*)d_out;

    char* ws = (char*)d_ws;
    unsigned long long* packed = (unsigned long long*)(ws);
    float* maxv   = (float*)(ws + 524288);
    int*   idx    = (int*)  (ws + 786432);
    int*   counts = (int*)  (ws + 1048576);
    float* accum  = (float*)(ws + 1310720);
    float* varS1  = (float*)(ws + 1310784);
    float* varS2  = (float*)(ws + 1441856);

    // zero: packed + (maxv/idx harmlessly) + counts + accum
    hipMemsetAsync(d_ws, 0, 1310728, stream);

    var1_kernel<<<128, 256, 0, stream>>>(x, b_dec, varS1, varS2);
    var2_kernel<<<8, 256, 0, stream>>>(varS1, varS2, accum);
    gemm_argmax_kernel<<<8192, 256, 0, stream>>>(x, encoder, b_enc, b_dec, packed);
    extract_kernel<<<256, 256, 0, stream>>>(packed, maxv, idx, counts);
    recon_kernel<<<BB, 256, 0, stream>>>(x, decoder, b_dec, maxv, idx, accum);
    finalize_kernel<<<256, 256, 0, stream>>>(accum, counts, out);
}